// Round 1
// baseline (691.724 us; speedup 1.0000x reference)
//
#include <hip/hip_runtime.h>
#include <stdint.h>

#define B_    32
#define H_    8
#define KLEN_ 8192
#define D_    64
#define SPLIT 16                              // blocks per (b,h)
#define ROWS_PER_BLOCK (KLEN_ / SPLIT)        // 512
#define WAVES 4
#define TILES (ROWS_PER_BLOCK / (WAVES * 16)) // 8 tiles of 16 rows per wave
#define TSTRIDE (WAVES * 16 * D_)             // f32 elems between a wave's consecutive tiles

typedef __attribute__((ext_vector_type(8))) short  short8;   // 8 bf16 (4 VGPRs)
typedef __attribute__((ext_vector_type(8))) float  float8;   // 32 B (2x dwordx4)
typedef __attribute__((ext_vector_type(4))) float  float4v;
typedef __attribute__((ext_vector_type(4))) unsigned int uint4v;

// pack two f32 -> bf16x2 dword (round-half-up; 2 adds + 1 v_perm_b32) — proven in baseline
static __device__ inline unsigned int pack_bf16(float x0, float x1) {
    unsigned int a = __builtin_bit_cast(unsigned int, x0) + 0x8000u;
    unsigned int b = __builtin_bit_cast(unsigned int, x1) + 0x8000u;
    return __builtin_amdgcn_perm(b, a, 0x07060302u);
}

static __device__ inline short8 pack8(float8 f) {
    uint4v p;
    #pragma unroll
    for (int j = 0; j < 4; ++j) p[j] = pack_bf16(f[2 * j], f[2 * j + 1]);
    return __builtin_bit_cast(short8, p);
}

__global__ __launch_bounds__(256, 4) void nais_score_kernel(
    const float* __restrict__ Q,    // [B,H,1,D]
    const float* __restrict__ K,    // [B,H,KLEN,D]
    const float* __restrict__ Wc,   // [H,2D,D]
    const float* __restrict__ Wo,   // [H,D,1]
    const float* __restrict__ bias, // [H,1,D]
    float* __restrict__ out)        // [B,H,KLEN]
{
    const int blk   = blockIdx.x;
    const int bh    = blk / SPLIT;
    const int split = blk % SPLIT;
    const int h     = bh % H_;
    const int tid   = threadIdx.x;
    const int lane  = tid & 63;
    const int wave  = tid >> 6;
    const int c     = lane & 15;   // A-row / C-col index
    const int q     = lane >> 4;   // quad

    // ---- issue the first 2 K tiles immediately (HBM latency hides under prologue) ----
    // A-fragment-layout direct load: lane (c,q) reads K row (tilebase + c),
    // f32 elems q*8..q*8+7 (af0) and 32+q*8.. (af1). A wave covers the same
    // 16 cache lines as a lane-contiguous load — equally coalesced, no LDS needed.
    const float* Kb    = K + (size_t)bh * (KLEN_ * D_) + (size_t)split * (ROWS_PER_BLOCK * D_);
    const float* lanep = Kb + (size_t)(wave * 16 + c) * D_ + q * 8;

    float8 f0[2], f1[2];   // all indices compile-time (full unroll) -> registers
    #pragma unroll
    for (int p = 0; p < 2; ++p) {
        f0[p] = *(const float8*)(lanep + p * TSTRIDE);
        f1[p] = *(const float8*)(lanep + p * TSTRIDE + 32);
    }

    // ---- q_proj[d=lane] = bias + Q·Wc[:64], per-wave redundant: no LDS, no syncs ----
    const float* qv = Q  + (size_t)bh * D_;
    const float* wq = Wc + (size_t)h * (2 * D_ * D_);
    const float* wk = wq + D_ * D_;

    float a0 = bias[h * D_ + lane], a1 = 0.f, a2 = 0.f, a3 = 0.f;
    #pragma unroll
    for (int e = 0; e < D_; e += 4) {
        a0 += qv[e]     * wq[(e)     * D_ + lane];
        a1 += qv[e + 1] * wq[(e + 1) * D_ + lane];
        a2 += qv[e + 2] * wq[(e + 2) * D_ + lane];
        a3 += qv[e + 3] * wq[(e + 3) * D_ + lane];
    }
    const float qp       = (a0 + a1) + (a2 + a3);
    const float wol_lane = Wo[h * D_ + lane];

    float qbl[4], wol[4];
    #pragma unroll
    for (int tt = 0; tt < 4; ++tt) {
        qbl[tt] = __shfl(qp,       tt * 16 + c);
        wol[tt] = __shfl(wol_lane, tt * 16 + c);
    }

    // ---- persistent B fragments: Wk[e][d], lane holds B[k=q*8+j][n=c] ----
    short8 bfrag[4][2];
    #pragma unroll
    for (int t = 0; t < 4; ++t) {
        const int d = t * 16 + c;
        #pragma unroll
        for (int half = 0; half < 2; ++half) {
            uint4v f;
            #pragma unroll
            for (int j2 = 0; j2 < 4; ++j2) {
                const int e = half * 32 + q * 8 + 2 * j2;
                f[j2] = pack_bf16(wk[(size_t)e * D_ + d], wk[(size_t)(e + 1) * D_ + d]);
            }
            bfrag[t][half] = __builtin_bit_cast(short8, f);
        }
    }

    // store base: one contiguous 64-B store per tile by the 16 lanes with c<4
    float* ob = out + (size_t)bh * KLEN_ + (size_t)split * ROWS_PER_BLOCK
              + wave * 16 + q * 4 + c;

    #pragma unroll
    for (int t = 0; t < TILES; ++t) {
        const int cur = t & 1;                 // compile-time under full unroll
        short8 af0 = pack8(f0[cur]);
        short8 af1 = pack8(f1[cur]);

        if (t + 2 < TILES) {                   // prefetch 2 ahead into freed slot
            f0[cur] = *(const float8*)(lanep + (t + 2) * TSTRIDE);
            f1[cur] = *(const float8*)(lanep + (t + 2) * TSTRIDE + 32);
        }

        float4v pr = {0.f, 0.f, 0.f, 0.f};
        #pragma unroll
        for (int tt = 0; tt < 4; ++tt) {
            // fold q_proj+bias into the accumulator init (C/D: col=c, row=q*4+r)
            float4v acc = {qbl[tt], qbl[tt], qbl[tt], qbl[tt]};
            acc = __builtin_amdgcn_mfma_f32_16x16x32_bf16(af0, bfrag[tt][0], acc, 0, 0, 0);
            acc = __builtin_amdgcn_mfma_f32_16x16x32_bf16(af1, bfrag[tt][1], acc, 0, 0, 0);
            #pragma unroll
            for (int r = 0; r < 4; ++r)
                pr[r] += fmaxf(acc[r], 0.f) * wol[tt];
        }

        // reduce over the 16 d-columns (xor within c-nibble)
        #pragma unroll
        for (int r = 0; r < 4; ++r) {
            pr[r] += __shfl_xor(pr[r], 1);
            pr[r] += __shfl_xor(pr[r], 2);
            pr[r] += __shfl_xor(pr[r], 4);
            pr[r] += __shfl_xor(pr[r], 8);
        }
        // select row's value without runtime indexing, single contiguous store
        const float v01 = (c & 1) ? pr[1] : pr[0];
        const float v23 = (c & 1) ? pr[3] : pr[2];
        const float v   = (c & 2) ? v23 : v01;
        if (c < 4) ob[t * (WAVES * 16)] = v;   // rows (t*4+wave)*16 + q*4 + c
    }
}

extern "C" void kernel_launch(void* const* d_in, const int* in_sizes, int n_in,
                              void* d_out, int out_size, void* d_ws, size_t ws_size,
                              hipStream_t stream) {
    const float* Q    = (const float*)d_in[0];
    const float* K    = (const float*)d_in[1];
    const float* Wc   = (const float*)d_in[2];
    const float* Wo   = (const float*)d_in[3];
    const float* bias = (const float*)d_in[4];
    float* out = (float*)d_out;

    dim3 grid(B_ * H_ * SPLIT);  // 4096 blocks
    dim3 block(256);
    nais_score_kernel<<<grid, block, 0, stream>>>(Q, K, Wc, Wo, bias, out);
}